// Round 7
// baseline (411.798 us; speedup 1.0000x reference)
//
#include <hip/hip_runtime.h>
#include <hip/hip_bf16.h>

#define N_NODES 50000
#define N_EDGES 1000000
#define C       128
#define N_REL   8
#define N_SEG   (N_NODES * N_REL)       // 400000
#define KTOT    (N_REL * C + C)         // 1152 = 8 rel chunks + self
#define KC_CNT  (KTOT / 32)             // 36 MFMA k-chunks
#define A_STRIDE 1160                   // 1152 + 8 bf16 pad per row
#define NCHUNK  ((N_SEG + 1023) / 1024) // 391 scan chunks
#define NBLK    (N_NODES / 16)          // 3125 layer blocks
#define FE_BLK  ((N_EDGES + 511) / 512) // 1954 fill edge-blocks

typedef __hip_bfloat16  bf16;
typedef __hip_bfloat162 bf162;
typedef unsigned long long u64;
typedef __attribute__((ext_vector_type(8))) short short8;
typedef __attribute__((ext_vector_type(4))) float f32x4;
typedef __attribute__((ext_vector_type(2))) unsigned int uint2v;

// ---------------------------------------------------------------- weight fragment index
// B-fragment for mfma_f32_16x16x32_bf16: lane = quad*16 + (n&15) holds
// B[k = kc*32 + quad*8 + j][n], j=0..7 contiguous.
__device__ __forceinline__ size_t frag_index(int k, int n) {
    int nt = n >> 4, n15 = n & 15;
    int kc = k >> 5, quad = (k >> 3) & 3, j = k & 7;
    int lane = quad * 16 + n15;
    return ((size_t)(nt * KC_CNT + kc) * 64 + lane) * 8 + j;
}

// ---------------------------------------------------------------- prep: cvt + count + repacks
// R17: weight repacks moved here (independent of counts) so they overlap the
// atomic-heavy count phase instead of serializing in a later dispatch.
// Count atomic's return value IS the rank; packed (rank<<19 | seg) -> rankseg.
#define CVT_BLOCKS ((N_NODES * C / 4) / 256)          // 6250 (exact)
#define CNT_BLOCKS ((N_EDGES + 255) / 256)            // 3907
#define RP_B  (KTOT * C / 256)            // 576 repack1 blocks
#define RPT_B ((KTOT / 16) * (C / 16))    // 576 repack2 tiles
#define PREP_GRID (CVT_BLOCKS + CNT_BLOCKS + RP_B + RPT_B + 1)   // 11310
__global__ void prep_kernel(const float4* __restrict__ xf, uint2v* __restrict__ xb,
                            const int* __restrict__ dst, const int* __restrict__ et,
                            int* __restrict__ cnt, int* __restrict__ rankseg,
                            const float* __restrict__ W1, const float* __restrict__ root1,
                            const float* __restrict__ W2, const float* __restrict__ root2,
                            const float* __restrict__ linW,
                            const float* __restrict__ b2v, const float* __restrict__ linb,
                            bf16* __restrict__ Bp1, bf16* __restrict__ Bp2,
                            float* __restrict__ b2p) {
    __shared__ float Wt[16][128];    // 8 KB (repack2 only)
    __shared__ float Lt[128][16];    // 8 KB
    int bid = blockIdx.x;
    int t   = threadIdx.x;
    if (bid < CVT_BLOCKS) {
        int i = bid * 256 + t;
        float4 v = xf[i];
        union { bf162 h; unsigned int u; } c0, c1;
        c0.h = bf162(__float2bfloat16(v.x), __float2bfloat16(v.y));
        c1.h = bf162(__float2bfloat16(v.z), __float2bfloat16(v.w));
        uint2v o; o.x = c0.u; o.y = c1.u;
        xb[i] = o;
    } else if (bid < CVT_BLOCKS + CNT_BLOCKS) {
        int e = (bid - CVT_BLOCKS) * 256 + t;
        if (e < N_EDGES) {
            int seg = dst[e] * N_REL + et[e];
            int r = atomicAdd(&cnt[seg], 1);
            rankseg[e] = (r << 19) | seg;
        }
    } else if (bid < CVT_BLOCKS + CNT_BLOCKS + RP_B) {
        int idx = (bid - CVT_BLOCKS - CNT_BLOCKS) * 256 + t;
        int k = idx >> 7, n = idx & 127;
        float val;
        if (k < N_REL * C) val = W1[(size_t)k * C + n];
        else               val = root1[(size_t)(k - N_REL * C) * C + n];
        Bp1[frag_index(k, n)] = __float2bfloat16(val);
    } else if (bid < CVT_BLOCKS + CNT_BLOCKS + RP_B + RPT_B) {
        // tiled repack2: out(k0+ty, n0+tx) = sum_m W2cat[k0+ty][m] * linW[m][n0+tx]
        int tileid = bid - CVT_BLOCKS - CNT_BLOCKS - RP_B;
        int kt = tileid >> 3;            // 0..71 (k0 = kt*16; 1024 boundary not straddled)
        int n0 = (tileid & 7) * 16;
        int k0 = kt * 16;
        const float* baseW = (k0 < N_REL * C) ? (W2 + (size_t)k0 * C)
                                              : (root2 + (size_t)(k0 - N_REL * C) * C);
#pragma unroll
        for (int r = 0; r < 8; r++) {            // 2048 elems, coalesced
            int idx = t + r * 256;
            Wt[idx >> 7][idx & 127] = baseW[idx];
        }
#pragma unroll
        for (int r = 0; r < 8; r++) {            // 2048 elems: m = idx>>4, n = idx&15
            int idx = t + r * 256;
            Lt[idx >> 4][idx & 15] = linW[(size_t)(idx >> 4) * C + n0 + (idx & 15)];
        }
        __syncthreads();
        int ty = t >> 4, tx = t & 15;
        float acc = 0.f;
#pragma unroll 8
        for (int m = 0; m < 128; m++)
            acc += Wt[ty][m] * Lt[m][tx];
        Bp2[frag_index(k0 + ty, n0 + tx)] = __float2bfloat16(acc);
    } else {
        if (t < 128) {
            float acc = linb[t];
            for (int m = 0; m < C; m++)
                acc += b2v[m] * linW[(size_t)m * C + t];
            b2p[t] = acc;
        }
    }
}

// ---------------------------------------------------------------- scan: decoupled lookback
// R17: 391 blocks (all co-resident: grid << capacity -> no deadlock) write
// FINAL offsets in one pass. flagval[b] = (state<<32 | value); state 1 =
// chunk sum published, state 2 = inclusive prefix published. Agent-scope
// atomics for cross-XCD coherence of the flag; offs_f consumed next dispatch.
__global__ __launch_bounds__(512) void scan_kernel(const int* __restrict__ cnt,
                                                   u64* __restrict__ flagval,
                                                   int* __restrict__ offs_f) {
    __shared__ int tot[512];
    __shared__ int basesh;
    const int t = threadIdx.x, b = blockIdx.x;
    const int base = b * 1024 + t * 2;
    int v0 = (base     < N_SEG) ? cnt[base]     : 0;
    int v1 = (base + 1 < N_SEG) ? cnt[base + 1] : 0;
    int ts = v0 + v1;
    tot[t] = ts;
    __syncthreads();
    for (int d = 1; d < 512; d <<= 1) {
        int x = tot[t];
        int y = (t >= d) ? tot[t - d] : 0;
        __syncthreads();
        tot[t] = x + y;
        __syncthreads();
    }
    const int incl = tot[t];
    const int sum  = tot[511];
    if (t == 0) {
        if (b == 0) {
            __hip_atomic_store(&flagval[0], (2ULL << 32) | (unsigned)sum,
                               __ATOMIC_RELEASE, __HIP_MEMORY_SCOPE_AGENT);
            basesh = 0;
            offs_f[N_SEG] = N_EDGES;
        } else {
            __hip_atomic_store(&flagval[b], (1ULL << 32) | (unsigned)sum,
                               __ATOMIC_RELEASE, __HIP_MEMORY_SCOPE_AGENT);
            int acc = 0;
            int p = b - 1;
            while (p >= 0) {
                u64 v = __hip_atomic_load(&flagval[p], __ATOMIC_ACQUIRE,
                                          __HIP_MEMORY_SCOPE_AGENT);
                unsigned st = (unsigned)(v >> 32);
                if (st == 0) { __builtin_amdgcn_s_sleep(8); continue; }
                acc += (int)(unsigned)v;
                if (st == 2) break;      // inclusive prefix through p -> done
                p--;                      // partial: keep walking back
            }
            __hip_atomic_store(&flagval[b], (2ULL << 32) | (unsigned)(acc + sum),
                               __ATOMIC_RELEASE, __HIP_MEMORY_SCOPE_AGENT);
            basesh = acc;
        }
    }
    __syncthreads();
    const int cb = basesh;
    const int excl = incl - ts + cb;
    if (base     < N_SEG) offs_f[base]     = excl;
    if (base + 1 < N_SEG) offs_f[base + 1] = excl + v0;
}

// ---------------------------------------------------------------- fill: pure gather+scatter
// R17: no LDS, no barriers, no per-block scan -- offsets are already final.
__global__ __launch_bounds__(512) void fill_kernel(const int* __restrict__ src,
                                                   const int* __restrict__ rankseg,
                                                   const int* __restrict__ offs_f,
                                                   int* __restrict__ srcs_out) {
    int e = blockIdx.x * 512 + threadIdx.x;
    if (e < N_EDGES) {
        int rs = rankseg[e];
        int seg = rs & 0x7FFFF;
        int r = ((unsigned int)rs) >> 19;
        srcs_out[offs_f[seg] + r] = src[e];
    }
}

// ---------------------------------------------------------------- fused layer
// R0-proven body VERBATIM (73.3 us measured; 0/6 micro-opts helped -- frozen).
// 16 nodes/block, 512 threads (8 waves), wave w owns segments [16w,16w+16),
// explicit 2-stage gather pipeline, LDS offsL.
template <int RELU, int OUT_F32>
__global__ __launch_bounds__(512, 6) void fused_layer(
        const unsigned int* __restrict__ featu,  // [N][64] bf16 pairs
        const int*   __restrict__ offs,          // [N_SEG+1] final
        const int*   __restrict__ srcs,          // [N_EDGES]
        const short8* __restrict__ Bp,           // fragment-packed bf16 weights
        const float* __restrict__ bias,          // [128] fp32
        void* __restrict__ outp)                 // [N][128] fp32 or bf16
{
    __shared__ __align__(16) unsigned int At[16 * (A_STRIDE / 2)];  // bf16 pairs
    __shared__ int offsL[129];
    const int tid  = threadIdx.x;
    const int lane = tid & 63;
    const int w    = tid >> 6;          // 0..7
    const int v0   = blockIdx.x * 16;

    if (tid < 129) offsL[tid] = offs[v0 * 8 + tid];
    if (tid < 64)  At[(tid >> 2) * (A_STRIDE / 2) + 576 + (tid & 3)] = 0u;  // pad pairs

    // self rows -> k range [1024..1151]
    for (int q = tid; q < 16 * 64; q += 512) {
        int node = q >> 6, pch = q & 63;
        At[node * (A_STRIDE / 2) + 512 + pch] = featu[(size_t)(v0 + node) * 64 + pch];
    }
    __syncthreads();

    // ---- aggregation over wave-owned contiguous edge range (16 segments)
    {
        const int segLo = w * 16;
        const int segHi = segLo + 16;
        int curSeg = segLo;
        int segEnd = offsL[curSeg + 1];
        int i      = offsL[segLo];
        const int eend = offsL[segHi];
        float a0 = 0.f, a1 = 0.f;

        unsigned int vals[16];
        bool have = (i + 16 <= eend);
        if (have) {
            const int ib = __builtin_amdgcn_readfirstlane(i);
            int sv[16];
#pragma unroll
            for (int j = 0; j < 16; j++) sv[j] = srcs[ib + j];
#pragma unroll
            for (int j = 0; j < 16; j++) vals[j] = featu[(size_t)sv[j] * 64 + lane];
        }
        while (have) {
            const int inext = i + 16;
            const bool havenext = (inext + 16 <= eend);
            unsigned int vals2[16];
            if (havenext) {                       // prefetch batch k+1 (straight-line)
                const int ib2 = __builtin_amdgcn_readfirstlane(inext);
                int sv2[16];
#pragma unroll
                for (int j = 0; j < 16; j++) sv2[j] = srcs[ib2 + j];
#pragma unroll
                for (int j = 0; j < 16; j++) vals2[j] = featu[(size_t)sv2[j] * 64 + lane];
            }
            // fold batch k
#pragma unroll
            for (int j = 0; j < 16; j++) {
                while (i + j == segEnd) {         // flush finished segment(s)
                    int b = offsL[curSeg];
                    float inv = (segEnd > b) ? 1.0f / (float)(segEnd - b) : 0.0f;
                    union { bf162 h; unsigned int u; } cv;
                    cv.h = bf162(__float2bfloat16(a0 * inv), __float2bfloat16(a1 * inv));
                    At[(curSeg >> 3) * (A_STRIDE / 2) + (curSeg & 7) * 64 + lane] = cv.u;
                    a0 = 0.f; a1 = 0.f;
                    curSeg++;
                    segEnd = offsL[curSeg + 1];
                }
                union { bf162 h; unsigned int u; } uv; uv.u = vals[j];
                a0 += __low2float(uv.h);
                a1 += __high2float(uv.h);
            }
            i = inext;
            have = havenext;
            if (havenext) {
#pragma unroll
                for (int j = 0; j < 16; j++) vals[j] = vals2[j];
            }
        }
        // predicated tail batch (m < 16, wave-uniform)
        {
            int m = eend - i;
            const int ib = __builtin_amdgcn_readfirstlane(i);
            int sv[16];
#pragma unroll
            for (int j = 0; j < 16; j++) if (j < m) sv[j] = srcs[ib + j];
            unsigned int tvals[16];
#pragma unroll
            for (int j = 0; j < 16; j++) if (j < m) tvals[j] = featu[(size_t)sv[j] * 64 + lane];
#pragma unroll
            for (int j = 0; j < 16; j++) {
                if (j < m) {
                    while (i + j == segEnd) {
                        int b = offsL[curSeg];
                        float inv = (segEnd > b) ? 1.0f / (float)(segEnd - b) : 0.0f;
                        union { bf162 h; unsigned int u; } cv;
                        cv.h = bf162(__float2bfloat16(a0 * inv), __float2bfloat16(a1 * inv));
                        At[(curSeg >> 3) * (A_STRIDE / 2) + (curSeg & 7) * 64 + lane] = cv.u;
                        a0 = 0.f; a1 = 0.f;
                        curSeg++;
                        segEnd = offsL[curSeg + 1];
                    }
                    union { bf162 h; unsigned int u; } uv; uv.u = tvals[j];
                    a0 += __low2float(uv.h);
                    a1 += __high2float(uv.h);
                }
            }
        }
        // trailing flushes (last non-empty segment + empty tails)
        while (curSeg < segHi) {
            int b = offsL[curSeg], e2 = offsL[curSeg + 1];
            float inv = (e2 > b) ? 1.0f / (float)(e2 - b) : 0.0f;
            union { bf162 h; unsigned int u; } cv;
            cv.h = bf162(__float2bfloat16(a0 * inv), __float2bfloat16(a1 * inv));
            At[(curSeg >> 3) * (A_STRIDE / 2) + (curSeg & 7) * 64 + lane] = cv.u;
            a0 = 0.f; a1 = 0.f;
            curSeg++;
        }
    }
    __syncthreads();

    // ---- MFMA GEMM: wave w computes N-tile w (cols 16w..16w+15)
    const int quad = lane >> 4, n15 = lane & 15;
    f32x4 acc = {0.f, 0.f, 0.f, 0.f};
    const short* Ash = (const short*)At;

    short8 b0 = Bp[(size_t)(w * KC_CNT) * 64 + lane];
#pragma unroll 4
    for (int kc = 0; kc < KC_CNT; kc++) {
        short8 cb0 = b0;
        if (kc + 1 < KC_CNT)
            b0 = Bp[(size_t)(w * KC_CNT + kc + 1) * 64 + lane];
        short8 a = *reinterpret_cast<const short8*>(Ash + n15 * A_STRIDE + kc * 32 + quad * 8);
        acc = __builtin_amdgcn_mfma_f32_16x16x32_bf16(a, cb0, acc, 0, 0, 0);
    }

    // epilogue: D[m = quad*4 + r][col = w*16 + n15]
    {
        int col = w * 16 + n15;
        float bv = bias[col];
#pragma unroll
        for (int r = 0; r < 4; r++) {
            int m = quad * 4 + r;
            float v = acc[r] + bv;
            if (RELU) v = fmaxf(v, 0.f);
            if (OUT_F32) ((float*)outp)[(size_t)(v0 + m) * C + col] = v;
            else         ((bf16*)outp)[(size_t)(v0 + m) * C + col] = __float2bfloat16(v);
        }
    }
}

// ---------------------------------------------------------------- launch
// fp32 I/O. ZERO d_ws usage. Buffer provenance (R17 layout):
//   d_out      : [0..1.6M) cnt + [1.6M..+3128) flagval (memset covers both);
//                rankseg @ +1,603,328; xb16 @ +5,603,328 (all scratch, dead
//                before layer 2 overwrites d_out with the final output)
//   ei buffer  : [0..4MB) src (dead after fill); [4..8MB) dst (dead after
//                prep) -> srcs_final (fill)
//   et buffer  : et (dead after prep) -> offs_final (scan)
//   x buffer   : h1 bf16 low (x fp32 dead after cvt); packed weights high
extern "C" void kernel_launch(void* const* d_in, const int* in_sizes, int n_in,
                              void* d_out, int out_size, void* d_ws, size_t ws_size,
                              hipStream_t stream) {
    const float* x     = (const float*)d_in[0];
    const int*   ei    = (const int*)d_in[1];
    const int*   et    = (const int*)d_in[2];
    const float* W1    = (const float*)d_in[3];
    const float* root1 = (const float*)d_in[4];
    const float* b1    = (const float*)d_in[5];
    const float* W2    = (const float*)d_in[6];
    const float* root2 = (const float*)d_in[7];
    const float* b2    = (const float*)d_in[8];
    const float* linW  = (const float*)d_in[9];
    const float* linb  = (const float*)d_in[10];
    const int* src = ei;
    const int* dst = ei + N_EDGES;

    // ---- d_out scratch
    char* ob = (char*)d_out;
    int* cnt_i    = (int*)(ob + 0);            // 1,600,000 B
    u64* flagval  = (u64*)(ob + 1600000);      // 3,128 B (8-aligned); memset ends 1,603,128
    int* rankseg  = (int*)(ob + 1603328);      // 4,000,000 B -> ends 5,603,328
    unsigned int* xb16 = (unsigned int*)(ob + 5603328);  // 256-aligned; ends 18,403,328 < 25.6 MB

    // ---- final CSR in dead input buffers
    int* srcs_f = (int*)((char*)d_in[1] + 4000000);   // over dst (dead after prep)
    int* offs_f = (int*)d_in[2];                      // over et  (dead after prep)

    // ---- x buffer: h1 low, weights high
    char* xbuf = (char*)d_in[0];
    unsigned int* h1 = (unsigned int*)xbuf;          // 12.8 MB
    bf16*  Bp1 = (bf16*)(xbuf + 13000192);           // 16B-aligned, 294,912 B
    bf16*  Bp2 = (bf16*)(xbuf + 13295360);           // 294,912 B
    float* b2p = (float*)(xbuf + 13590528);          // 512 B -> ends < 25.6 MB

    float* out = (float*)d_out;

    hipMemsetAsync(cnt_i, 0, 1603128, stream);   // cnt + flagval
    prep_kernel<<<PREP_GRID, 256, 0, stream>>>(
        (const float4*)x, (uint2v*)xb16, dst, et, cnt_i, rankseg,
        W1, root1, W2, root2, linW, b2, linb, Bp1, Bp2, b2p);
    scan_kernel<<<NCHUNK, 512, 0, stream>>>(cnt_i, flagval, offs_f);
    fill_kernel<<<FE_BLK, 512, 0, stream>>>(src, rankseg, offs_f, srcs_f);

    fused_layer<1, 0><<<NBLK, 512, 0, stream>>>(
        xb16, offs_f, srcs_f, (const short8*)Bp1, b1, (void*)h1);
    fused_layer<0, 1><<<NBLK, 512, 0, stream>>>(
        h1, offs_f, srcs_f, (const short8*)Bp2, b2p, (void*)out);

    (void)in_sizes; (void)n_in; (void)out_size; (void)d_ws; (void)ws_size;
}

// Round 8
// 300.907 us; speedup vs baseline: 1.3685x; 1.3685x over previous
//
#include <hip/hip_runtime.h>
#include <hip/hip_bf16.h>

#define N_NODES 50000
#define N_EDGES 1000000
#define C       128
#define N_REL   8
#define N_SEG   (N_NODES * N_REL)       // 400000
#define KTOT    (N_REL * C + C)         // 1152 = 8 rel chunks + self
#define KC_CNT  (KTOT / 32)             // 36 MFMA k-chunks
#define A_STRIDE 1160                   // 1152 + 8 bf16 pad per row
#define NBLK    (N_NODES / 16)          // 3125 layer blocks
#define FE_BLK  ((N_EDGES + 511) / 512) // 1954 fill edge-blocks

typedef __hip_bfloat16  bf16;
typedef __hip_bfloat162 bf162;
typedef unsigned long long u64;
typedef __attribute__((ext_vector_type(8))) short short8;
typedef __attribute__((ext_vector_type(4))) float f32x4;
typedef __attribute__((ext_vector_type(2))) unsigned int uint2v;

// ---------------------------------------------------------------- weight fragment index
// B-fragment for mfma_f32_16x16x32_bf16: lane = quad*16 + (n&15) holds
// B[k = kc*32 + quad*8 + j][n], j=0..7 contiguous.
__device__ __forceinline__ size_t frag_index(int k, int n) {
    int nt = n >> 4, n15 = n & 15;
    int kc = k >> 5, quad = (k >> 3) & 3, j = k & 7;
    int lane = quad * 16 + n15;
    return ((size_t)(nt * KC_CNT + kc) * 64 + lane) * 8 + j;
}

// ---------------------------------------------------------------- prep: cvt + count + repacks
// Weight repacks overlap the atomic-heavy count phase (independent work).
// Count atomic's return value IS the rank; packed (rank<<19 | seg) -> rankseg.
#define CVT_BLOCKS ((N_NODES * C / 4) / 256)          // 6250 (exact)
#define CNT_BLOCKS ((N_EDGES + 255) / 256)            // 3907
#define RP_B  (KTOT * C / 256)            // 576 repack1 blocks
#define RPT_B ((KTOT / 16) * (C / 16))    // 576 repack2 tiles
#define PREP_GRID (CVT_BLOCKS + CNT_BLOCKS + RP_B + RPT_B + 1)   // 11310
__global__ void prep_kernel(const float4* __restrict__ xf, uint2v* __restrict__ xb,
                            const int* __restrict__ dst, const int* __restrict__ et,
                            int* __restrict__ cnt, int* __restrict__ rankseg,
                            const float* __restrict__ W1, const float* __restrict__ root1,
                            const float* __restrict__ W2, const float* __restrict__ root2,
                            const float* __restrict__ linW,
                            const float* __restrict__ b2v, const float* __restrict__ linb,
                            bf16* __restrict__ Bp1, bf16* __restrict__ Bp2,
                            float* __restrict__ b2p) {
    __shared__ float Wt[16][128];    // 8 KB (repack2 only)
    __shared__ float Lt[128][16];    // 8 KB
    int bid = blockIdx.x;
    int t   = threadIdx.x;
    if (bid < CVT_BLOCKS) {
        int i = bid * 256 + t;
        float4 v = xf[i];
        union { bf162 h; unsigned int u; } c0, c1;
        c0.h = bf162(__float2bfloat16(v.x), __float2bfloat16(v.y));
        c1.h = bf162(__float2bfloat16(v.z), __float2bfloat16(v.w));
        uint2v o; o.x = c0.u; o.y = c1.u;
        xb[i] = o;
    } else if (bid < CVT_BLOCKS + CNT_BLOCKS) {
        int e = (bid - CVT_BLOCKS) * 256 + t;
        if (e < N_EDGES) {
            int seg = dst[e] * N_REL + et[e];
            int r = atomicAdd(&cnt[seg], 1);
            rankseg[e] = (r << 19) | seg;
        }
    } else if (bid < CVT_BLOCKS + CNT_BLOCKS + RP_B) {
        int idx = (bid - CVT_BLOCKS - CNT_BLOCKS) * 256 + t;
        int k = idx >> 7, n = idx & 127;
        float val;
        if (k < N_REL * C) val = W1[(size_t)k * C + n];
        else               val = root1[(size_t)(k - N_REL * C) * C + n];
        Bp1[frag_index(k, n)] = __float2bfloat16(val);
    } else if (bid < CVT_BLOCKS + CNT_BLOCKS + RP_B + RPT_B) {
        // tiled repack2: out(k0+ty, n0+tx) = sum_m W2cat[k0+ty][m] * linW[m][n0+tx]
        int tileid = bid - CVT_BLOCKS - CNT_BLOCKS - RP_B;
        int kt = tileid >> 3;            // 0..71 (k0 = kt*16; 1024 boundary not straddled)
        int n0 = (tileid & 7) * 16;
        int k0 = kt * 16;
        const float* baseW = (k0 < N_REL * C) ? (W2 + (size_t)k0 * C)
                                              : (root2 + (size_t)(k0 - N_REL * C) * C);
#pragma unroll
        for (int r = 0; r < 8; r++) {            // 2048 elems, coalesced
            int idx = t + r * 256;
            Wt[idx >> 7][idx & 127] = baseW[idx];
        }
#pragma unroll
        for (int r = 0; r < 8; r++) {            // 2048 elems: m = idx>>4, n = idx&15
            int idx = t + r * 256;
            Lt[idx >> 4][idx & 15] = linW[(size_t)(idx >> 4) * C + n0 + (idx & 15)];
        }
        __syncthreads();
        int ty = t >> 4, tx = t & 15;
        float acc = 0.f;
#pragma unroll 8
        for (int m = 0; m < 128; m++)
            acc += Wt[ty][m] * Lt[m][tx];
        Bp2[frag_index(k0 + ty, n0 + tx)] = __float2bfloat16(acc);
    } else {
        if (t < 128) {
            float acc = linb[t];
            for (int m = 0; m < C; m++)
                acc += b2v[m] * linW[(size_t)m * C + t];
            b2p[t] = acc;
        }
    }
}

// ---------------------------------------------------------------- scan: 64-block wave-parallel lookback
// R18: R7's scan was 118 us because the lookback walked ~390 flags with
// SERIAL dependent loads (~0.3 us each). Fix: 64 blocks (6656 elems each,
// staged in LDS, coalesced in/out) + ONE wave-parallel flag round (lane l
// spins on flag[l], l < b). 64 blocks << 256 CUs -> co-resident, no deadlock.
#define SCB  64              // scan blocks
#define SRUN 13              // elems per thread
#define SPB  (512 * SRUN)    // 6656 elems per block; 64*6656 = 425,984 >= N_SEG
__global__ __launch_bounds__(512) void scan_kernel(const int* __restrict__ cnt,
                                                   u64* __restrict__ flagval,
                                                   int* __restrict__ offs_f) {
    __shared__ int ld[SPB];      // 26,624 B
    __shared__ int tsum[512];
    __shared__ int pre[SCB];
    const int t = threadIdx.x, b = blockIdx.x;
    const int base = b * SPB;
#pragma unroll
    for (int j = 0; j < SRUN; j++) {             // coalesced stage-in
        int idx = t + j * 512;
        int g = base + idx;
        ld[idx] = (g < N_SEG) ? cnt[g] : 0;
    }
    __syncthreads();
    // thread-local exclusive scan over contiguous run [t*SRUN, t*SRUN+SRUN)
    const int run = t * SRUN;
    int s = 0;
#pragma unroll
    for (int j = 0; j < SRUN; j++) { int v = ld[run + j]; ld[run + j] = s; s += v; }
    tsum[t] = s;
    __syncthreads();
    for (int d = 1; d < 512; d <<= 1) {          // block inclusive scan of thread sums
        int x = tsum[t];
        int y = (t >= d) ? tsum[t - d] : 0;
        __syncthreads();
        tsum[t] = x + y;
        __syncthreads();
    }
    const int texcl = tsum[t] - s;
    const int bsum  = tsum[511];
    if (t == 0) {
        __hip_atomic_store(&flagval[b], (1ULL << 32) | (unsigned)bsum,
                           __ATOMIC_RELEASE, __HIP_MEMORY_SCOPE_AGENT);
        if (b == 0) offs_f[N_SEG] = N_EDGES;
    }
    // wave-parallel lookback: lane l (< b) watches flag[l]; one round, no serial walk
    if (t < 64 && t < b) {
        u64 v;
        do {
            v = __hip_atomic_load(&flagval[t], __ATOMIC_ACQUIRE,
                                  __HIP_MEMORY_SCOPE_AGENT);
            if (!(v >> 32)) __builtin_amdgcn_s_sleep(2);
        } while (!(v >> 32));
        pre[t] = (int)(unsigned)v;
    }
    __syncthreads();
    int bbase = 0;
    for (int p = 0; p < b; p++) bbase += pre[p];     // <=63 adds, b uniform
#pragma unroll
    for (int j = 0; j < SRUN; j++) ld[run + j] += texcl;   // finalize in LDS
    __syncthreads();
#pragma unroll
    for (int j = 0; j < SRUN; j++) {             // coalesced stage-out
        int idx = t + j * 512;
        int g = base + idx;
        if (g < N_SEG) offs_f[g] = ld[idx] + bbase;
    }
}

// ---------------------------------------------------------------- fill: pure gather+scatter
__global__ __launch_bounds__(512) void fill_kernel(const int* __restrict__ src,
                                                   const int* __restrict__ rankseg,
                                                   const int* __restrict__ offs_f,
                                                   int* __restrict__ srcs_out) {
    int e = blockIdx.x * 512 + threadIdx.x;
    if (e < N_EDGES) {
        int rs = rankseg[e];
        int seg = rs & 0x7FFFF;
        int r = ((unsigned int)rs) >> 19;
        srcs_out[offs_f[seg] + r] = src[e];
    }
}

// ---------------------------------------------------------------- fused layer
// R0-proven body VERBATIM (73.3 us measured; frozen -- all 6 micro-opt
// attempts were neutral/negative; HBM rate pinned ~1.7 TB/s = random-access
// ceiling). 16 nodes/block, 512 threads (8 waves), wave w owns segments
// [16w,16w+16), explicit 2-stage gather pipeline, LDS offsL.
template <int RELU, int OUT_F32>
__global__ __launch_bounds__(512, 6) void fused_layer(
        const unsigned int* __restrict__ featu,  // [N][64] bf16 pairs
        const int*   __restrict__ offs,          // [N_SEG+1] final
        const int*   __restrict__ srcs,          // [N_EDGES]
        const short8* __restrict__ Bp,           // fragment-packed bf16 weights
        const float* __restrict__ bias,          // [128] fp32
        void* __restrict__ outp)                 // [N][128] fp32 or bf16
{
    __shared__ __align__(16) unsigned int At[16 * (A_STRIDE / 2)];  // bf16 pairs
    __shared__ int offsL[129];
    const int tid  = threadIdx.x;
    const int lane = tid & 63;
    const int w    = tid >> 6;          // 0..7
    const int v0   = blockIdx.x * 16;

    if (tid < 129) offsL[tid] = offs[v0 * 8 + tid];
    if (tid < 64)  At[(tid >> 2) * (A_STRIDE / 2) + 576 + (tid & 3)] = 0u;  // pad pairs

    // self rows -> k range [1024..1151]
    for (int q = tid; q < 16 * 64; q += 512) {
        int node = q >> 6, pch = q & 63;
        At[node * (A_STRIDE / 2) + 512 + pch] = featu[(size_t)(v0 + node) * 64 + pch];
    }
    __syncthreads();

    // ---- aggregation over wave-owned contiguous edge range (16 segments)
    {
        const int segLo = w * 16;
        const int segHi = segLo + 16;
        int curSeg = segLo;
        int segEnd = offsL[curSeg + 1];
        int i      = offsL[segLo];
        const int eend = offsL[segHi];
        float a0 = 0.f, a1 = 0.f;

        unsigned int vals[16];
        bool have = (i + 16 <= eend);
        if (have) {
            const int ib = __builtin_amdgcn_readfirstlane(i);
            int sv[16];
#pragma unroll
            for (int j = 0; j < 16; j++) sv[j] = srcs[ib + j];
#pragma unroll
            for (int j = 0; j < 16; j++) vals[j] = featu[(size_t)sv[j] * 64 + lane];
        }
        while (have) {
            const int inext = i + 16;
            const bool havenext = (inext + 16 <= eend);
            unsigned int vals2[16];
            if (havenext) {                       // prefetch batch k+1 (straight-line)
                const int ib2 = __builtin_amdgcn_readfirstlane(inext);
                int sv2[16];
#pragma unroll
                for (int j = 0; j < 16; j++) sv2[j] = srcs[ib2 + j];
#pragma unroll
                for (int j = 0; j < 16; j++) vals2[j] = featu[(size_t)sv2[j] * 64 + lane];
            }
            // fold batch k
#pragma unroll
            for (int j = 0; j < 16; j++) {
                while (i + j == segEnd) {         // flush finished segment(s)
                    int b = offsL[curSeg];
                    float inv = (segEnd > b) ? 1.0f / (float)(segEnd - b) : 0.0f;
                    union { bf162 h; unsigned int u; } cv;
                    cv.h = bf162(__float2bfloat16(a0 * inv), __float2bfloat16(a1 * inv));
                    At[(curSeg >> 3) * (A_STRIDE / 2) + (curSeg & 7) * 64 + lane] = cv.u;
                    a0 = 0.f; a1 = 0.f;
                    curSeg++;
                    segEnd = offsL[curSeg + 1];
                }
                union { bf162 h; unsigned int u; } uv; uv.u = vals[j];
                a0 += __low2float(uv.h);
                a1 += __high2float(uv.h);
            }
            i = inext;
            have = havenext;
            if (havenext) {
#pragma unroll
                for (int j = 0; j < 16; j++) vals[j] = vals2[j];
            }
        }
        // predicated tail batch (m < 16, wave-uniform)
        {
            int m = eend - i;
            const int ib = __builtin_amdgcn_readfirstlane(i);
            int sv[16];
#pragma unroll
            for (int j = 0; j < 16; j++) if (j < m) sv[j] = srcs[ib + j];
            unsigned int tvals[16];
#pragma unroll
            for (int j = 0; j < 16; j++) if (j < m) tvals[j] = featu[(size_t)sv[j] * 64 + lane];
#pragma unroll
            for (int j = 0; j < 16; j++) {
                if (j < m) {
                    while (i + j == segEnd) {
                        int b = offsL[curSeg];
                        float inv = (segEnd > b) ? 1.0f / (float)(segEnd - b) : 0.0f;
                        union { bf162 h; unsigned int u; } cv;
                        cv.h = bf162(__float2bfloat16(a0 * inv), __float2bfloat16(a1 * inv));
                        At[(curSeg >> 3) * (A_STRIDE / 2) + (curSeg & 7) * 64 + lane] = cv.u;
                        a0 = 0.f; a1 = 0.f;
                        curSeg++;
                        segEnd = offsL[curSeg + 1];
                    }
                    union { bf162 h; unsigned int u; } uv; uv.u = tvals[j];
                    a0 += __low2float(uv.h);
                    a1 += __high2float(uv.h);
                }
            }
        }
        // trailing flushes (last non-empty segment + empty tails)
        while (curSeg < segHi) {
            int b = offsL[curSeg], e2 = offsL[curSeg + 1];
            float inv = (e2 > b) ? 1.0f / (float)(e2 - b) : 0.0f;
            union { bf162 h; unsigned int u; } cv;
            cv.h = bf162(__float2bfloat16(a0 * inv), __float2bfloat16(a1 * inv));
            At[(curSeg >> 3) * (A_STRIDE / 2) + (curSeg & 7) * 64 + lane] = cv.u;
            a0 = 0.f; a1 = 0.f;
            curSeg++;
        }
    }
    __syncthreads();

    // ---- MFMA GEMM: wave w computes N-tile w (cols 16w..16w+15)
    const int quad = lane >> 4, n15 = lane & 15;
    f32x4 acc = {0.f, 0.f, 0.f, 0.f};
    const short* Ash = (const short*)At;

    short8 b0 = Bp[(size_t)(w * KC_CNT) * 64 + lane];
#pragma unroll 4
    for (int kc = 0; kc < KC_CNT; kc++) {
        short8 cb0 = b0;
        if (kc + 1 < KC_CNT)
            b0 = Bp[(size_t)(w * KC_CNT + kc + 1) * 64 + lane];
        short8 a = *reinterpret_cast<const short8*>(Ash + n15 * A_STRIDE + kc * 32 + quad * 8);
        acc = __builtin_amdgcn_mfma_f32_16x16x32_bf16(a, cb0, acc, 0, 0, 0);
    }

    // epilogue: D[m = quad*4 + r][col = w*16 + n15]
    {
        int col = w * 16 + n15;
        float bv = bias[col];
#pragma unroll
        for (int r = 0; r < 4; r++) {
            int m = quad * 4 + r;
            float v = acc[r] + bv;
            if (RELU) v = fmaxf(v, 0.f);
            if (OUT_F32) ((float*)outp)[(size_t)(v0 + m) * C + col] = v;
            else         ((bf16*)outp)[(size_t)(v0 + m) * C + col] = __float2bfloat16(v);
        }
    }
}

// ---------------------------------------------------------------- launch
// fp32 I/O. ZERO d_ws usage. Buffer provenance (R18 layout):
//   d_out      : [0..1.6M) cnt + [1.6M..+512) flagval (memset covers both);
//                rankseg @ +1,603,328; xb16 @ +5,603,328 (all scratch, dead
//                before layer 2 overwrites d_out with the final output)
//   ei buffer  : [0..4MB) src (dead after fill); [4..8MB) dst (dead after
//                prep) -> srcs_final (fill)
//   et buffer  : et (dead after prep) -> offs_final (scan)
//   x buffer   : h1 bf16 low (x fp32 dead after cvt); packed weights high
extern "C" void kernel_launch(void* const* d_in, const int* in_sizes, int n_in,
                              void* d_out, int out_size, void* d_ws, size_t ws_size,
                              hipStream_t stream) {
    const float* x     = (const float*)d_in[0];
    const int*   ei    = (const int*)d_in[1];
    const int*   et    = (const int*)d_in[2];
    const float* W1    = (const float*)d_in[3];
    const float* root1 = (const float*)d_in[4];
    const float* b1    = (const float*)d_in[5];
    const float* W2    = (const float*)d_in[6];
    const float* root2 = (const float*)d_in[7];
    const float* b2    = (const float*)d_in[8];
    const float* linW  = (const float*)d_in[9];
    const float* linb  = (const float*)d_in[10];
    const int* src = ei;
    const int* dst = ei + N_EDGES;

    // ---- d_out scratch
    char* ob = (char*)d_out;
    int* cnt_i    = (int*)(ob + 0);            // 1,600,000 B
    u64* flagval  = (u64*)(ob + 1600000);      // 512 B (8-aligned); memset ends 1,600,512
    int* rankseg  = (int*)(ob + 1603328);      // 4,000,000 B -> ends 5,603,328
    unsigned int* xb16 = (unsigned int*)(ob + 5603328);  // 256-aligned; ends 18,403,328 < 25.6 MB

    // ---- final CSR in dead input buffers
    int* srcs_f = (int*)((char*)d_in[1] + 4000000);   // over dst (dead after prep)
    int* offs_f = (int*)d_in[2];                      // over et  (dead after prep)

    // ---- x buffer: h1 low, weights high
    char* xbuf = (char*)d_in[0];
    unsigned int* h1 = (unsigned int*)xbuf;          // 12.8 MB
    bf16*  Bp1 = (bf16*)(xbuf + 13000192);           // 16B-aligned, 294,912 B
    bf16*  Bp2 = (bf16*)(xbuf + 13295360);           // 294,912 B
    float* b2p = (float*)(xbuf + 13590528);          // 512 B -> ends < 25.6 MB

    float* out = (float*)d_out;

    hipMemsetAsync(cnt_i, 0, 1600512, stream);   // cnt + flagval
    prep_kernel<<<PREP_GRID, 256, 0, stream>>>(
        (const float4*)x, (uint2v*)xb16, dst, et, cnt_i, rankseg,
        W1, root1, W2, root2, linW, b2, linb, Bp1, Bp2, b2p);
    scan_kernel<<<SCB, 512, 0, stream>>>(cnt_i, flagval, offs_f);
    fill_kernel<<<FE_BLK, 512, 0, stream>>>(src, rankseg, offs_f, srcs_f);

    fused_layer<1, 0><<<NBLK, 512, 0, stream>>>(
        xb16, offs_f, srcs_f, (const short8*)Bp1, b1, (void*)h1);
    fused_layer<0, 1><<<NBLK, 512, 0, stream>>>(
        h1, offs_f, srcs_f, (const short8*)Bp2, b2p, (void*)out);

    (void)in_sizes; (void)n_in; (void)out_size; (void)d_ws; (void)ws_size;
}